// Round 2
// baseline (40.175 us; speedup 1.0000x reference)
//
#include <hip/hip_runtime.h>

// Problem constants (fixed by setup_inputs: B=64, PER=512, N_COMPOUND=112)
constexpr int PERN = 512;
constexpr int NCMP = 112;
constexpr int BATCHES = 64;
constexpr float INTRA_CUT = 1.6f;   // 8.0 / 5.0
constexpr float INTER_CUT = 2.0f;   // 10.0 / 5.0
constexpr int ROWS_PER_BLOCK = 16;  // 32 blocks per batch

__global__ __launch_bounds__(256) void pair_mask_kernel(
    const float* __restrict__ X, float* __restrict__ out)
{
    // Swizzled point tile for one batch: slot = p ^ ((p>>3)&7) spreads the
    // 128B-strided per-lane float4 reads across all 32 banks (<=2-way, free).
    __shared__ float4 pt[PERN];

    const int tid = threadIdx.x;
    const int blk = blockIdx.x;
    const int b = blk / (PERN / ROWS_PER_BLOCK);
    const int row0 = (blk % (PERN / ROWS_PER_BLOCK)) * ROWS_PER_BLOCK;

    // Stage this batch's 512 points (1536 floats) into LDS, transposing to
    // swizzled float4 slots. Coalesced global reads; LDS writes scattered (cheap).
    const float* Xb = X + (size_t)b * PERN * 3;
    for (int f = tid; f < PERN * 3; f += 256) {
        int p = f / 3;
        int c = f - p * 3;
        int slot = p ^ ((p >> 3) & 7);
        reinterpret_cast<float*>(&pt[slot])[c] = Xb[f];
    }
    __syncthreads();

    const int lane = tid & 63;   // j-group within row
    const int sub = tid >> 6;    // which of 4 rows this pass
    const int j0 = lane << 3;    // 8 consecutive j per lane
    const size_t NP = (size_t)BATCHES * PERN * PERN;  // elements per plane

    for (int pass = 0; pass < ROWS_PER_BLOCK / 4; ++pass) {
        const int li = row0 + pass * 4 + sub;          // local row index
        const int sloti = li ^ ((li >> 3) & 7);
        const float4 pi = pt[sloti];                   // broadcast-ish read
        const bool rg = (li == 0) | (li == NCMP);      // row is_global
        const int  sr = (li >= NCMP);                  // row segment
        const size_t base = ((size_t)(b * PERN + li)) * PERN + (size_t)j0;

        float c8[8], i8[8], m8[8];

#pragma unroll
        for (int k = 0; k < 8; ++k) {
            const int j = j0 + k;
            const int slot = j ^ ((j >> 3) & 7);
            const float4 pj = pt[slot];
            const float dx = pi.x - pj.x;
            const float dy = pi.y - pj.y;
            const float dz = pi.z - pj.z;
            const float d2 = dx * dx + dy * dy + dz * dz;
            const bool valid = (j != li);
            const bool fin = valid & (d2 > 0.0f);      // dist finite in ref
            const float dist = sqrtf(d2);
            const bool cgl = (j == 0) | (j == NCMP);   // col is_global (raw)
            const bool cg = cgl & valid;
            const bool notg = !(rg | cg);
            const int  sj = (j >= NCMP);
            const bool same = valid & (sr == sj);
            const bool ctxr  = same & (sr == 1) & notg & fin & (dist <= INTRA_CUT);
            const bool inter = valid & (sr != sj) & notg & fin & (dist <= INTER_CUT);
            const bool gnorm = same & (!notg);
            const bool gg    = valid & rg & cgl;
            const bool ctx   = ctxr | gnorm | gg;
            c8[k] = ctx ? 1.0f : 0.0f;
            i8[k] = inter ? 1.0f : 0.0f;
            m8[k] = ((ctx | inter) & fin) ? dist : 0.0f;
        }

        float* o0 = out + base;
        float* o1 = out + NP + base;
        float* o2 = out + 2 * NP + base;
        *reinterpret_cast<float4*>(o0)     = make_float4(c8[0], c8[1], c8[2], c8[3]);
        *reinterpret_cast<float4*>(o0 + 4) = make_float4(c8[4], c8[5], c8[6], c8[7]);
        *reinterpret_cast<float4*>(o1)     = make_float4(i8[0], i8[1], i8[2], i8[3]);
        *reinterpret_cast<float4*>(o1 + 4) = make_float4(i8[4], i8[5], i8[6], i8[7]);
        *reinterpret_cast<float4*>(o2)     = make_float4(m8[0], m8[1], m8[2], m8[3]);
        *reinterpret_cast<float4*>(o2 + 4) = make_float4(m8[4], m8[5], m8[6], m8[7]);
    }
}

extern "C" void kernel_launch(void* const* d_in, const int* in_sizes, int n_in,
                              void* d_out, int out_size, void* d_ws, size_t ws_size,
                              hipStream_t stream) {
    const float* X = (const float*)d_in[0];
    float* out = (float*)d_out;
    const int grid = BATCHES * (PERN / ROWS_PER_BLOCK);  // 2048 blocks
    pair_mask_kernel<<<grid, 256, 0, stream>>>(X, out);
}